// Round 3
// baseline (113.186 us; speedup 1.0000x reference)
//
#include <hip/hip_runtime.h>
#include <stdint.h>

// DSVDD fused: dist = sqrt(||phi||^2 + ||c||^2 - 2 phi.c), top-3 smallest, softmin score.
// bf16 MFMA computes S = phi.c - ||c||^2/2 (centers folded into K-pad 112->128),
// track top-3 LARGEST S per row, finalize with sqrt+softmin.
// R3: barrier-free main loop. Each wave owns an m-slice and streams its af fragments
// DIRECTLY global->VGPR from L2 (CT unswizzled, 64B granules), double-buffered in named
// registers. phi fragments in registers (64 VGPR/wave: wave covers 64 of the block's
// 128 rows). No LDS in the main loop at all -> no per-mt barriers, no vmcnt drains.

typedef short s16x8 __attribute__((ext_vector_type(8)));
typedef float fx4 __attribute__((ext_vector_type(4)));

#define M_TOT 3136
#define CC 112
#define N_MTILES 25  // 3200 / 128

__device__ __forceinline__ unsigned short f2bf(float x) {
  unsigned u = __float_as_uint(x);
  u += 0x7fffu + ((u >> 16) & 1u);  // RNE
  return (unsigned short)(u >> 16);
}

// insert v into descending triple (t0 >= t1 >= t2), keep 3 largest. 3 VALU ops.
#define INSERT3(T0, T1, T2, V)                                  \
  do {                                                          \
    const float _a0 = (T0), _a1 = (T1), _v = (V);               \
    (T0) = fmaxf(_a0, _v);                                      \
    (T1) = __builtin_amdgcn_fmed3f(_a0, _a1, _v);               \
    (T2) = __builtin_amdgcn_fmed3f(_a1, (T2), _v);              \
  } while (0)

// ---- prep: C_bank (112 x 3136 f32) -> CT (3200 x 128 bf16, UNSWIZZLED), centers folded
// CT[m][k]: k=0..111 = C_bank[k][m]; k=112..115 = -||c_m||^2/8 (or -2500 sentinel); rest 0.
__global__ __launch_bounds__(256) void dsvdd_prep(const float* __restrict__ Cb,
                                                  unsigned char* __restrict__ CTg) {
  const int i = threadIdx.x & 63;
  const int q = threadIdx.x >> 6;
  const int m = blockIdx.x * 64 + i;
  const bool valid = (m < M_TOT);
  __shared__ float part[4][64];
  float ss = 0.f;
  const int b0 = q * 4;
  const int nb = (q == 3) ? 2 : 4;  // blocks 14,15 are special
  for (int jb = 0; jb < nb; ++jb) {
    const int b = b0 + jb;
    float v[8];
#pragma unroll
    for (int j = 0; j < 8; ++j) {
      v[j] = valid ? Cb[(size_t)(b * 8 + j) * M_TOT + m] : 0.f;
      ss += v[j] * v[j];
    }
    uint4 pk;
    pk.x = (unsigned)f2bf(v[0]) | ((unsigned)f2bf(v[1]) << 16);
    pk.y = (unsigned)f2bf(v[2]) | ((unsigned)f2bf(v[3]) << 16);
    pk.z = (unsigned)f2bf(v[4]) | ((unsigned)f2bf(v[5]) << 16);
    pk.w = (unsigned)f2bf(v[6]) | ((unsigned)f2bf(v[7]) << 16);
    *(uint4*)(CTg + (size_t)m * 256 + b * 16) = pk;
  }
  part[q][i] = ss;
  __syncthreads();
  if (q == 0) {
    const float c2 = part[0][i] + part[1][i] + part[2][i] + part[3][i];
    const float slot = valid ? (-0.125f * c2) : -2500.0f;  // sentinel: S ~ -1e4
    const unsigned sb = f2bf(slot);
    const unsigned ww = sb | (sb << 16);
    uint4 blk;
    blk.x = ww; blk.y = ww; blk.z = 0u; blk.w = 0u;
    *(uint4*)(CTg + (size_t)m * 256 + 14 * 16) = blk;
    uint4 zz;
    zz.x = zz.y = zz.z = zz.w = 0u;
    *(uint4*)(CTg + (size_t)m * 256 + 15 * 16) = zz;
  }
}

// ---- main: 128 phi rows per 512-thread block (8 waves = 2 row-groups x 4 m-slices) ----
__global__ __launch_bounds__(512, 2) void dsvdd_main(const float* __restrict__ phi,
                                                     const unsigned char* __restrict__ CTg,
                                                     float* __restrict__ out) {
  __shared__ __align__(16) unsigned char phi_lds[128 * 256];  // 32 KB, swizzled bf16
  __shared__ float feat_lds[128];
  float(*const merge_lds)[17] = (float(*)[17])phi_lds;  // epilogue alias

  const int t = threadIdx.x;
  const int lane = t & 63;
  const int w = t >> 6;   // 0..7
  const int g = w >> 2;   // row-group: rows [g*64, g*64+64)
  const int ms = w & 3;   // m-slice: rows [ms*32, ms*32+32) of each 128-m tile
  const int cq = lane & 15;
  const int kq = lane >> 4;
  const int sw = lane & 7;
  const long rowBase = (long)blockIdx.x * 128;

  // ---- prologue: stage phi fp32 -> bf16 (swizzled) into LDS; features fp32 ----
  if (t < 256) {
    const int r = t >> 1;
    const int half = t & 1;
    const float* src = phi + (rowBase + r) * CC + half * 56;
    float ss = 0.f;
#pragma unroll
    for (int j = 0; j < 7; ++j) {
      const float4 v0 = *(const float4*)(src + j * 8);
      const float4 v1 = *(const float4*)(src + j * 8 + 4);
      ss += v0.x * v0.x + v0.y * v0.y + v0.z * v0.z + v0.w * v0.w;
      ss += v1.x * v1.x + v1.y * v1.y + v1.z * v1.z + v1.w * v1.w;
      uint4 pk;
      pk.x = (unsigned)f2bf(v0.x) | ((unsigned)f2bf(v0.y) << 16);
      pk.y = (unsigned)f2bf(v0.z) | ((unsigned)f2bf(v0.w) << 16);
      pk.z = (unsigned)f2bf(v1.x) | ((unsigned)f2bf(v1.y) << 16);
      pk.w = (unsigned)f2bf(v1.z) | ((unsigned)f2bf(v1.w) << 16);
      const int b = half * 7 + j;
      *(uint4*)(phi_lds + r * 256 + ((b ^ (r & 7)) * 16)) = pk;
    }
    {  // K-pad: block14 = {1,1,1,1,0,0,0,0} (fold slots), block15 = 0
      const int b = 14 + half;
      uint4 pk;
      if (half == 0) {
        pk.x = 0x3f803f80u; pk.y = 0x3f803f80u; pk.z = 0u; pk.w = 0u;
      } else {
        pk.x = pk.y = pk.z = pk.w = 0u;
      }
      *(uint4*)(phi_lds + r * 256 + ((b ^ (r & 7)) * 16)) = pk;
    }
    ss += __shfl_xor(ss, 1);
    if (half == 0) feat_lds[r] = ss;
  }
  __syncthreads();

  // ---- phi fragments for this wave's 64 rows: 64 VGPRs, held all kernel ----
  s16x8 bg[4][4];  // [ks][pf]
#pragma unroll
  for (int ks = 0; ks < 4; ++ks)
#pragma unroll
    for (int pf = 0; pf < 4; ++pf)
      bg[ks][pf] = *(const s16x8*)(phi_lds + (g * 64 + pf * 16 + cq) * 256 +
                                   (((ks * 4 + kq) ^ sw) * 16));

  float t0[4], t1[4], t2[4];
#pragma unroll
  for (int pf = 0; pf < 4; ++pf) t0[pf] = t1[pf] = t2[pf] = -3.0e38f;

  // ---- barrier-free main loop: stream af fragments global->reg, double-buffered ----
  const unsigned char* ap = CTg + (size_t)(ms * 32 + cq) * 256 + kq * 16;
  // af byte offset(mt, mf, ks) = mt*32768 + mf*4096 + ks*64

  s16x8 afA[8], afB[8];  // named buffers (no runtime indexing -> stays in registers)

#define LOADAF(DST, MT)                                                       \
  do {                                                                        \
    const unsigned char* _p = ap + (size_t)(MT)*32768;                        \
    _Pragma("unroll") for (int mf = 0; mf < 2; ++mf)                          \
        _Pragma("unroll") for (int ks = 0; ks < 4; ++ks)                      \
            DST[mf * 4 + ks] = *(const s16x8*)(_p + mf * 4096 + ks * 64);     \
  } while (0)

#define COMPUTE(SRC)                                                          \
  do {                                                                        \
    const fx4 _zz = {0.f, 0.f, 0.f, 0.f};                                     \
    _Pragma("unroll") for (int mf = 0; mf < 2; ++mf) {                        \
      fx4 acc[4];                                                             \
      _Pragma("unroll") for (int ks = 0; ks < 4; ++ks)                        \
          _Pragma("unroll") for (int pf = 0; pf < 4; ++pf)                    \
              acc[pf] = __builtin_amdgcn_mfma_f32_16x16x32_bf16(              \
                  SRC[mf * 4 + ks], bg[ks][pf], (ks == 0) ? _zz : acc[pf],    \
                  0, 0, 0);                                                   \
      _Pragma("unroll") for (int pf = 0; pf < 4; ++pf)                        \
          _Pragma("unroll") for (int rg = 0; rg < 4; ++rg)                    \
              INSERT3(t0[pf], t1[pf], t2[pf], acc[pf][rg]);                   \
    }                                                                         \
  } while (0)

  LOADAF(afA, 0);
  for (int mtp = 0; mtp < 12; ++mtp) {  // covers mt = 0..23; af for mt=24 loaded in last iter
    LOADAF(afB, 2 * mtp + 1);
    COMPUTE(afA);
    __builtin_amdgcn_s_barrier();  // pacing only (no LDS dep): keeps wave pairs L1-coherent
    LOADAF(afA, 2 * mtp + 2);
    COMPUTE(afB);
  }
  COMPUTE(afA);  // mt = 24

#undef LOADAF
#undef COMPUTE

  // ---- merge the 4 kq groups within the wave ----
#pragma unroll
  for (int pf = 0; pf < 4; ++pf) {
#pragma unroll
    for (int off = 16; off < 64; off <<= 1) {
      const float b0 = __shfl_xor(t0[pf], off);
      const float b1 = __shfl_xor(t1[pf], off);
      const float b2 = __shfl_xor(t2[pf], off);
      INSERT3(t0[pf], t1[pf], t2[pf], b0);
      INSERT3(t0[pf], t1[pf], t2[pf], b1);
      INSERT3(t0[pf], t1[pf], t2[pf], b2);
    }
  }
  __syncthreads();  // everyone past phi_lds reads; safe to alias merge_lds onto it
  if (kq == 0) {
#pragma unroll
    for (int pf = 0; pf < 4; ++pf) {
      const int row = g * 64 + pf * 16 + cq;
      merge_lds[row][ms * 4 + 0] = t0[pf];
      merge_lds[row][ms * 4 + 1] = t1[pf];
      merge_lds[row][ms * 4 + 2] = t2[pf];
    }
  }
  __syncthreads();

  // ---- finalize: merge the 4 m-slices, sqrt, softmin, write ----
  if (t < 128) {
    float s0 = merge_lds[t][0], s1 = merge_lds[t][1], s2 = merge_lds[t][2];
#pragma unroll
    for (int ww2 = 1; ww2 < 4; ++ww2) {
      INSERT3(s0, s1, s2, merge_lds[t][ww2 * 4 + 0]);
      INSERT3(s0, s1, s2, merge_lds[t][ww2 * 4 + 1]);
      INSERT3(s0, s1, s2, merge_lds[t][ww2 * 4 + 2]);
    }
    const float feat = feat_lds[t];
    const float d0 = sqrtf(fmaxf(feat - 2.f * s0, 0.f));
    const float d1 = sqrtf(fmaxf(feat - 2.f * s1, 0.f));
    const float d2 = sqrtf(fmaxf(feat - 2.f * s2, 0.f));
    const float w0 = 1.0f / (1.0f + __expf(d0 - d1) + __expf(d0 - d2));
    out[rowBase + t] = w0 * d0;
  }
}

extern "C" void kernel_launch(void* const* d_in, const int* in_sizes, int n_in,
                              void* d_out, int out_size, void* d_ws, size_t ws_size,
                              hipStream_t stream) {
  (void)in_sizes; (void)n_in; (void)out_size; (void)ws_size;
  const float* phi = (const float*)d_in[0];
  const float* Cb = (const float*)d_in[1];
  float* out = (float*)d_out;
  unsigned char* CTg = (unsigned char*)d_ws;  // 3200*128*2 = 819200 B
  dsvdd_prep<<<50, 256, 0, stream>>>(Cb, CTg);
  dsvdd_main<<<392, 512, 0, stream>>>(phi, CTg, out);
}

// Round 4
// 79.226 us; speedup vs baseline: 1.4286x; 1.4286x over previous
//
#include <hip/hip_runtime.h>
#include <stdint.h>

// DSVDD fused: dist = sqrt(||phi||^2 + ||c||^2 - 2 phi.c), top-3 smallest, softmin score.
// bf16 MFMA computes S = phi.c - ||c||^2/2 (centers folded into K-pad 112->128),
// track top-3 LARGEST S per row == 3 smallest distances.
// R4: two-stage. Stage1: grid (392 row-blocks x S m-chunks), 256 thr / 4 waves,
// wave = 64 rows x 32 m. phi direct global->reg (64 VGPR), CT via global_load_lds
// into 32KB LDS dbuf (64-m tiles, one barrier/tile), 4 blocks/CU. Stage2: merge
// S partial top-3 per row + sqrt + softmin. ws: CT | feat | partials.

typedef short s16x8 __attribute__((ext_vector_type(8)));
typedef float fx4 __attribute__((ext_vector_type(4)));

#define M_TOT 3136
#define CC 112
#define NROWS 50176
#define N_TILES_TOT 50  // 3200 m / 64 per tile

__device__ __forceinline__ unsigned short f2bf(float x) {
  unsigned u = __float_as_uint(x);
  u += 0x7fffu + ((u >> 16) & 1u);  // RNE
  return (unsigned short)(u >> 16);
}

__device__ __forceinline__ void async16(const void* g, void* l) {
  __builtin_amdgcn_global_load_lds(
      (const __attribute__((address_space(1))) unsigned int*)g,
      (__attribute__((address_space(3))) unsigned int*)l, 16, 0, 0);
}

// insert v into descending triple (t0 >= t1 >= t2), keep 3 largest. 3 VALU ops.
#define INSERT3(T0, T1, T2, V)                                  \
  do {                                                          \
    const float _a0 = (T0), _a1 = (T1), _v = (V);               \
    (T0) = fmaxf(_a0, _v);                                      \
    (T1) = __builtin_amdgcn_fmed3f(_a0, _a1, _v);               \
    (T2) = __builtin_amdgcn_fmed3f(_a1, (T2), _v);              \
  } while (0)

// ---- prep: C_bank (112 x 3136 f32) -> CT (3200 x 128 bf16), centers folded ----
// CT[m][k]: k=0..111 = C_bank[k][m]; k=112..115 = -||c_m||^2/8 (sentinel -2500); rest 0.
// 16B-block b of row m stored at byte (b ^ (m&15))*16  (bank swizzle for ds_read_b128).
__global__ __launch_bounds__(256) void dsvdd_prep(const float* __restrict__ Cb,
                                                  unsigned char* __restrict__ CTg) {
  const int i = threadIdx.x & 63;
  const int q = threadIdx.x >> 6;
  const int m = blockIdx.x * 64 + i;
  const bool valid = (m < M_TOT);
  __shared__ float part[4][64];
  float ss = 0.f;
  const int b0 = q * 4;
  const int nb = (q == 3) ? 2 : 4;  // blocks 14,15 are special
  for (int jb = 0; jb < nb; ++jb) {
    const int b = b0 + jb;
    float v[8];
#pragma unroll
    for (int j = 0; j < 8; ++j) {
      v[j] = valid ? Cb[(size_t)(b * 8 + j) * M_TOT + m] : 0.f;
      ss += v[j] * v[j];
    }
    uint4 pk;
    pk.x = (unsigned)f2bf(v[0]) | ((unsigned)f2bf(v[1]) << 16);
    pk.y = (unsigned)f2bf(v[2]) | ((unsigned)f2bf(v[3]) << 16);
    pk.z = (unsigned)f2bf(v[4]) | ((unsigned)f2bf(v[5]) << 16);
    pk.w = (unsigned)f2bf(v[6]) | ((unsigned)f2bf(v[7]) << 16);
    *(uint4*)(CTg + (size_t)m * 256 + ((b ^ (m & 15)) * 16)) = pk;
  }
  part[q][i] = ss;
  __syncthreads();
  if (q == 0) {
    const float c2 = part[0][i] + part[1][i] + part[2][i] + part[3][i];
    const float slot = valid ? (-0.125f * c2) : -2500.0f;  // sentinel: S = -1e4
    const unsigned sb = f2bf(slot);
    const unsigned ww = sb | (sb << 16);
    uint4 blk;
    blk.x = ww; blk.y = ww; blk.z = 0u; blk.w = 0u;
    *(uint4*)(CTg + (size_t)m * 256 + ((14 ^ (m & 15)) * 16)) = blk;
    uint4 zz;
    zz.x = zz.y = zz.z = zz.w = 0u;
    *(uint4*)(CTg + (size_t)m * 256 + ((15 ^ (m & 15)) * 16)) = zz;
  }
}

// ---- stage1: block = 128 rows x (nT tiles of 64 m); 4 waves = 2 row-groups x 2 m-halves
__global__ __launch_bounds__(256, 4) void dsvdd_stage1(const float* __restrict__ phi,
                                                       const unsigned char* __restrict__ CTg,
                                                       float* __restrict__ part,
                                                       float* __restrict__ featg, int nT) {
  __shared__ __align__(16) unsigned char lds[32768];
  unsigned char* const buf0 = lds;
  unsigned char* const buf1 = lds + 16384;

  const int t = threadIdx.x;
  const int lane = t & 63;
  const int w = t >> 6;
  const int g = w >> 1;  // row-group: rows [g*64, g*64+64)
  const int h = w & 1;   // m-half of each 64-m tile: [h*32, h*32+32)
  const int cq = lane & 15;
  const int kq = lane >> 4;
  const int c = blockIdx.y;
  const int tile0 = c * nT;
  const long rowBase = (long)blockIdx.x * 128;

  // issue CT tile0 stage early (overlaps the phi prologue)
  {
    const unsigned char* gsrc = CTg + (size_t)tile0 * 16384 + w * 1024 + lane * 16;
    unsigned char* ldst = buf0 + w * 1024;
#pragma unroll
    for (int r = 0; r < 4; ++r) async16(gsrc + r * 4096, ldst + r * 4096);
  }

  // ---- phi -> bg fragments directly (64 rows/wave, 64 VGPR) + row features ----
  s16x8 bg[4][4];  // [ks][pf]
  float ssr[4];
#pragma unroll
  for (int pf = 0; pf < 4; ++pf) {
    ssr[pf] = 0.f;
    const float* rp = phi + (size_t)(rowBase + g * 64 + pf * 16 + cq) * CC;
#pragma unroll
    for (int ks = 0; ks < 4; ++ks) {
      const int k0 = ks * 32 + kq * 8;
      s16x8 v;
      if (k0 <= 104) {  // 8 in-bounds f32
        const float4 a = *(const float4*)(rp + k0);
        const float4 b = *(const float4*)(rp + k0 + 4);
        ssr[pf] += a.x * a.x + a.y * a.y + a.z * a.z + a.w * a.w;
        ssr[pf] += b.x * b.x + b.y * b.y + b.z * b.z + b.w * b.w;
        v[0] = (short)f2bf(a.x); v[1] = (short)f2bf(a.y);
        v[2] = (short)f2bf(a.z); v[3] = (short)f2bf(a.w);
        v[4] = (short)f2bf(b.x); v[5] = (short)f2bf(b.y);
        v[6] = (short)f2bf(b.z); v[7] = (short)f2bf(b.w);
      } else if (k0 == 112) {  // fold slots: four 1.0, four 0
        v[0] = v[1] = v[2] = v[3] = (short)0x3f80;
        v[4] = v[5] = v[6] = v[7] = 0;
      } else {
        v = (s16x8)0;
      }
      bg[ks][pf] = v;
    }
    ssr[pf] += __shfl_xor(ssr[pf], 16);
    ssr[pf] += __shfl_xor(ssr[pf], 32);
  }
  if (c == 0 && kq == 0) {
#pragma unroll
    for (int pf = 0; pf < 4; ++pf)
      featg[rowBase + g * 64 + pf * 16 + cq] = ssr[pf];
  }

  float t0[4], t1[4], t2[4];
#pragma unroll
  for (int pf = 0; pf < 4; ++pf) t0[pf] = t1[pf] = t2[pf] = -3.0e38f;

  __syncthreads();  // tile0 landed (barrier drains vmcnt)

  for (int tt = 0; tt < nT; ++tt) {
    const unsigned char* rd = (tt & 1) ? buf1 : buf0;
    unsigned char* wr = (tt & 1) ? buf0 : buf1;
    if (tt + 1 < nT) {  // stage next tile into the buffer freed at the previous barrier
      const unsigned char* gsrc =
          CTg + (size_t)(tile0 + tt + 1) * 16384 + w * 1024 + lane * 16;
      unsigned char* ldst = wr + w * 1024;
#pragma unroll
      for (int r = 0; r < 4; ++r) async16(gsrc + r * 4096, ldst + r * 4096);
    }
#pragma unroll
    for (int mf = 0; mf < 2; ++mf) {
      const unsigned char* abase = rd + (h * 32 + mf * 16 + cq) * 256;
      s16x8 af[4];
#pragma unroll
      for (int ks = 0; ks < 4; ++ks)
        af[ks] = *(const s16x8*)(abase + (((ks * 4 + kq) ^ cq) * 16));
      fx4 acc[4];
      const fx4 zz = {0.f, 0.f, 0.f, 0.f};
#pragma unroll
      for (int ks = 0; ks < 4; ++ks)
#pragma unroll
        for (int pf = 0; pf < 4; ++pf)
          acc[pf] = __builtin_amdgcn_mfma_f32_16x16x32_bf16(
              af[ks], bg[ks][pf], (ks == 0) ? zz : acc[pf], 0, 0, 0);
#pragma unroll
      for (int pf = 0; pf < 4; ++pf)
#pragma unroll
        for (int rg = 0; rg < 4; ++rg)
          INSERT3(t0[pf], t1[pf], t2[pf], acc[pf][rg]);
    }
    __syncthreads();  // next tile landed + everyone done reading rd
  }

  // ---- merge the 4 kq groups within each wave ----
#pragma unroll
  for (int pf = 0; pf < 4; ++pf) {
#pragma unroll
    for (int off = 16; off < 64; off <<= 1) {
      const float b0 = __shfl_xor(t0[pf], off);
      const float b1 = __shfl_xor(t1[pf], off);
      const float b2 = __shfl_xor(t2[pf], off);
      INSERT3(t0[pf], t1[pf], t2[pf], b0);
      INSERT3(t0[pf], t1[pf], t2[pf], b1);
      INSERT3(t0[pf], t1[pf], t2[pf], b2);
    }
  }
  // merge the 2 m-halves via LDS (alias buf0; all CT reads finished at last barrier)
  float(*const mg)[8] = (float(*)[8])lds;  // [128 rows][h*3+..]
  if (kq == 0) {
#pragma unroll
    for (int pf = 0; pf < 4; ++pf) {
      const int row = g * 64 + pf * 16 + cq;
      mg[row][h * 3 + 0] = t0[pf];
      mg[row][h * 3 + 1] = t1[pf];
      mg[row][h * 3 + 2] = t2[pf];
    }
  }
  __syncthreads();
  if (t < 128) {
    float s0 = mg[t][0], s1 = mg[t][1], s2 = mg[t][2];
    INSERT3(s0, s1, s2, mg[t][3]);
    INSERT3(s0, s1, s2, mg[t][4]);
    INSERT3(s0, s1, s2, mg[t][5]);
    float* dst = part + ((size_t)c * NROWS + rowBase + t) * 3;
    dst[0] = s0; dst[1] = s1; dst[2] = s2;
  }
}

// ---- stage2: merge S partial triples per row, sqrt + softmin, write score ----
__global__ __launch_bounds__(256) void dsvdd_stage2(const float* __restrict__ part,
                                                    const float* __restrict__ featg,
                                                    float* __restrict__ out, int S) {
  const int row = blockIdx.x * 256 + threadIdx.x;
  if (row >= NROWS) return;
  float s0 = -3.0e38f, s1 = -3.0e38f, s2 = -3.0e38f;
  for (int c = 0; c < S; ++c) {
    const float* p = part + ((size_t)c * NROWS + row) * 3;
    INSERT3(s0, s1, s2, p[0]);
    INSERT3(s0, s1, s2, p[1]);
    INSERT3(s0, s1, s2, p[2]);
  }
  const float feat = featg[row];
  const float d0 = sqrtf(fmaxf(feat - 2.f * s0, 0.f));
  const float d1 = sqrtf(fmaxf(feat - 2.f * s1, 0.f));
  const float d2 = sqrtf(fmaxf(feat - 2.f * s2, 0.f));
  const float w0 = 1.0f / (1.0f + __expf(d0 - d1) + __expf(d0 - d2));
  out[row] = w0 * d0;
}

extern "C" void kernel_launch(void* const* d_in, const int* in_sizes, int n_in,
                              void* d_out, int out_size, void* d_ws, size_t ws_size,
                              hipStream_t stream) {
  (void)in_sizes; (void)n_in; (void)out_size;
  const float* phi = (const float*)d_in[0];
  const float* Cb = (const float*)d_in[1];
  float* out = (float*)d_out;
  unsigned char* CTg = (unsigned char*)d_ws;              // 819200 B
  float* featg = (float*)((unsigned char*)d_ws + 819200); // 200704 B
  float* partp = (float*)((unsigned char*)d_ws + 819200 + 200704);
  const size_t base = 819200 + 200704;
  int S = 1;
  if (ws_size >= base + (size_t)5 * NROWS * 12) S = 5;
  else if (ws_size >= base + (size_t)2 * NROWS * 12) S = 2;
  const int nT = N_TILES_TOT / S;
  dsvdd_prep<<<50, 256, 0, stream>>>(Cb, CTg);
  dsvdd_stage1<<<dim3(392, S), 256, 0, stream>>>(phi, CTg, partp, featg, nT);
  dsvdd_stage2<<<196, 256, 0, stream>>>(partp, featg, out, S);
}